// Round 1
// baseline (936.153 us; speedup 1.0000x reference)
//
#include <hip/hip_runtime.h>
#include <math.h>

#define BB 256
#define SS 512
#define VV 768
#define TT 513   // S+1
#define HH 50

// workspace layout (float offsets)
#define OFF_M1    0
#define OFF_M2    (OFF_M1 + BB*VV)                    // 196608
#define OFF_XPART (OFF_M2 + BB*VV)                    // 393216 ; 4 parts x B x 772
#define XPART_STRIDE 772
#define OFF_AROW  (OFF_XPART + 4*BB*XPART_STRIDE)     // 1183744 ; stride 520 per b
#define AROW_STRIDE 520
#define OFF_COLM  (OFF_AROW + BB*AROW_STRIDE)         // 1316864
#define OFF_COLRD (OFF_COLM + 520)                    // 1317384
#define OFF_YPART (OFF_COLRD + 520)                   // 1317904 ; 4 parts x B x V
// total = 2,104,336 floats = 8.42 MB (same footprint as prior verified kernel)

// ---------------- K0: mean of o1 only (atomic partial sums, 8 s-chunks) --------
__global__ __launch_bounds__(192) void k_mean1(const float* __restrict__ o1,
                                               float* __restrict__ ws) {
    int bid   = blockIdx.x;            // b*8 + chunk
    int chunk = bid & 7;
    int b     = bid >> 3;
    float* dst = ws + OFF_M1 + b * VV;
    int tid = threadIdx.x;             // 0..191, one float4 column each
    const float4* p = (const float4*)(o1 + (size_t)b * SS * VV + (size_t)chunk * 64 * VV) + tid;
    float4 acc = {0.f, 0.f, 0.f, 0.f};
#pragma unroll 4
    for (int s = 0; s < 64; ++s) {
        float4 x = p[(size_t)s * 192];
        acc.x += x.x; acc.y += x.y; acc.z += x.z; acc.w += x.w;
    }
    const float inv = 1.0f / 512.0f;
    float* d4 = dst + tid * 4;
    atomicAdd(d4 + 0, acc.x * inv);
    atomicAdd(d4 + 1, acc.y * inv);
    atomicAdd(d4 + 2, acc.z * inv);
    atomicAdd(d4 + 3, acc.w * inv);
}

// ---------------- K1: fused o2 pass — m2 partial sums + y-scores ---------------
// arow[b,t] = m1[b] . x2[b,t]   (t = 0..511), m2 accumulated in same read.
__global__ __launch_bounds__(256) void k_o2fused(const float* __restrict__ o2,
                                                 float* __restrict__ ws) {
    int bid = blockIdx.x;              // b*8 + tc
    int tc = bid & 7, b = bid >> 3;
    int tid = threadIdx.x, wave = tid >> 6, lane = tid & 63;
    const float4* m14 = (const float4*)(ws + OFF_M1 + b * VV);
    float4 mf0 = m14[lane], mf1 = m14[lane + 64], mf2 = m14[lane + 128];
    const float* base = o2 + (size_t)b * SS * VV;
    float* arow = ws + OFF_AROW + b * AROW_STRIDE;
    float4 s0 = {0,0,0,0}, s1 = {0,0,0,0}, s2 = {0,0,0,0};
    int t0 = tc * 64 + wave * 16;
#pragma unroll 2
    for (int i = 0; i < 16; ++i) {
        int t = t0 + i;
        const float4* r4 = (const float4*)(base + (size_t)t * VV);
        float4 x0 = r4[lane], x1 = r4[lane + 64], x2 = r4[lane + 128];
        s0.x += x0.x; s0.y += x0.y; s0.z += x0.z; s0.w += x0.w;
        s1.x += x1.x; s1.y += x1.y; s1.z += x1.z; s1.w += x1.w;
        s2.x += x2.x; s2.y += x2.y; s2.z += x2.z; s2.w += x2.w;
        float p = x0.x*mf0.x + x0.y*mf0.y + x0.z*mf0.z + x0.w*mf0.w
                + x1.x*mf1.x + x1.y*mf1.y + x1.z*mf1.z + x1.w*mf1.w
                + x2.x*mf2.x + x2.y*mf2.y + x2.z*mf2.z + x2.w*mf2.w;
#pragma unroll
        for (int off = 32; off > 0; off >>= 1) p += __shfl_down(p, off);
        if (lane == 0) arow[t] = p;
    }
    // reduce the 4 waves' column partials in LDS, then one atomicAdd per column
    __shared__ __align__(16) float red[4][VV];
    float4* my4 = (float4*)red[wave];
    my4[lane] = s0; my4[lane + 64] = s1; my4[lane + 128] = s2;
    __syncthreads();
    const float inv = 1.0f / 512.0f;
#pragma unroll
    for (int j = 0; j < 3; ++j) {
        int col = tid + 256 * j;
        float s = red[0][col] + red[1][col] + red[2][col] + red[3][col];
        atomicAdd(ws + OFF_M2 + b * VV + col, s * inv);
    }
}

// ---------------- K2: virtual y-score row t=S: arow[b,S] = m1[b].m2[b] ---------
__global__ __launch_bounds__(64) void k_vrow(float* __restrict__ ws) {
    int b = blockIdx.x, lane = threadIdx.x;
    const float4* m14 = (const float4*)(ws + OFF_M1 + b * VV);
    const float4* m24 = (const float4*)(ws + OFF_M2 + b * VV);
    float p = 0.f;
#pragma unroll
    for (int k = 0; k < 3; ++k) {
        float4 a = m14[lane + 64 * k], c = m24[lane + 64 * k];
        p += a.x*c.x + a.y*c.y + a.z*c.z + a.w*c.w;
    }
#pragma unroll
    for (int off = 32; off > 0; off >>= 1) p += __shfl_down(p, off);
    if (lane == 0) ws[OFF_AROW + b * AROW_STRIDE + SS] = p;
}

// ---------------- K3: per-column (t) softmax stats over b ----------------------
__global__ __launch_bounds__(256) void k_colstats(float* __restrict__ ws) {
    int t = blockIdx.x;                // 0..512
    int tid = threadIdx.x;             // thread = b
    int wave = tid >> 6, lane = tid & 63;
    float v = ws[OFF_AROW + tid * AROW_STRIDE + t];
    __shared__ float red[4], red2[4];
    float m = v;
#pragma unroll
    for (int off = 32; off > 0; off >>= 1) m = fmaxf(m, __shfl_down(m, off));
    if (lane == 0) red[wave] = m;
    __syncthreads();
    float m0 = fmaxf(fmaxf(red[0], red[1]), fmaxf(red[2], red[3]));
    float e = __expf(v - m0);
#pragma unroll
    for (int off = 32; off > 0; off >>= 1) e += __shfl_down(e, off);
    if (lane == 0) red2[wave] = e;
    __syncthreads();
    if (tid == 0) {
        float D = red2[0] + red2[1] + red2[2] + red2[3];
        ws[OFF_COLM + t]  = m0;
        ws[OFF_COLRD + t] = 1.0f / D;
    }
}

// ---------------- K4: x-side online softmax over s (per (b, quarter)) ----------
// register-prefetched staging: chunk c+1 loads overlap chunk c compute
#define XCHUNK 8
__global__ __launch_bounds__(256) void k_xside(const float* __restrict__ o1,
                                               float* __restrict__ ws) {
    int part = blockIdx.x & 3;
    int b    = blockIdx.x >> 2;
    int tid  = threadIdx.x;
    int wave = tid >> 6, lane = tid & 63;
    __shared__ __align__(16) float tile[XCHUNK][VV];
    __shared__ float sc[XCHUNK];

    // m2 fragment in registers (score phase uses lane-mapped float4s)
    const float4* m24 = (const float4*)(ws + OFF_M2 + b * VV);
    float4 mf0 = m24[lane], mf1 = m24[lane + 64], mf2 = m24[lane + 128];

    int s0 = part * 128;
    const float4* base4 = (const float4*)(o1 + (size_t)b * SS * VV + (size_t)s0 * VV);

    // prefetch chunk 0 into registers
    float4 r0 = base4[tid],        r1 = base4[256 + tid],  r2 = base4[512 + tid],
           r3 = base4[768 + tid],  r4 = base4[1024 + tid], r5 = base4[1280 + tid];

    float accv0 = 0.f, accv1 = 0.f, accv2 = 0.f;
    float M = -1e30f, d = 0.f;

    for (int c = 0; c < 128 / XCHUNK; ++c) {
        // commit staged registers to LDS
        float4* l4 = (float4*)&tile[0][0];
        l4[tid] = r0; l4[256 + tid] = r1; l4[512 + tid] = r2;
        l4[768 + tid] = r3; l4[1024 + tid] = r4; l4[1280 + tid] = r5;
        // issue next chunk's loads (latency hides under this chunk's compute)
        if (c < 128 / XCHUNK - 1) {
            const float4* g = base4 + (size_t)(c + 1) * (XCHUNK * VV / 4);
            r0 = g[tid]; r1 = g[256 + tid]; r2 = g[512 + tid];
            r3 = g[768 + tid]; r4 = g[1024 + tid]; r5 = g[1280 + tid];
        }
        __syncthreads();
        // scores: wave w computes rows 2w, 2w+1 via ds_read_b128
#pragma unroll
        for (int r2i = 0; r2i < 2; ++r2i) {
            int row = wave * 2 + r2i;
            const float4* trow = (const float4*)&tile[row][0];
            float4 a0 = trow[lane], a1 = trow[lane + 64], a2 = trow[lane + 128];
            float p = a0.x*mf0.x + a0.y*mf0.y + a0.z*mf0.z + a0.w*mf0.w
                    + a1.x*mf1.x + a1.y*mf1.y + a1.z*mf1.z + a1.w*mf1.w
                    + a2.x*mf2.x + a2.y*mf2.y + a2.z*mf2.z + a2.w*mf2.w;
#pragma unroll
            for (int off = 32; off > 0; off >>= 1) p += __shfl_down(p, off);
            if (lane == 0) sc[row] = p;
        }
        __syncthreads();
        float sv[XCHUNK], cmax = -1e30f;
#pragma unroll
        for (int j = 0; j < XCHUNK; ++j) { sv[j] = sc[j]; cmax = fmaxf(cmax, sv[j]); }
        float newM  = fmaxf(M, cmax);
        float scale = __expf(M - newM);
        float w[XCHUNK], wsum = 0.f;
#pragma unroll
        for (int j = 0; j < XCHUNK; ++j) { w[j] = __expf(sv[j] - newM); wsum += w[j]; }
        d = d * scale + wsum;
        {
            float a0 = accv0 * scale, a1 = accv1 * scale, a2 = accv2 * scale;
#pragma unroll
            for (int j = 0; j < XCHUNK; ++j) {
                a0 += w[j] * tile[j][tid];
                a1 += w[j] * tile[j][tid + 256];
                a2 += w[j] * tile[j][tid + 512];
            }
            accv0 = a0; accv1 = a1; accv2 = a2;
        }
        M = newM;
        __syncthreads();
    }

    if (part == 3) {  // virtual mean row: data = m1[b], score = m1.m2
        const float* m1p = ws + OFF_M1 + b * VV;
        for (int i = tid; i < VV; i += 256) tile[0][i] = m1p[i];
        __syncthreads();
        if (wave == 0) {
            const float4* trow = (const float4*)&tile[0][0];
            float4 a0 = trow[lane], a1 = trow[lane + 64], a2 = trow[lane + 128];
            float p = a0.x*mf0.x + a0.y*mf0.y + a0.z*mf0.z + a0.w*mf0.w
                    + a1.x*mf1.x + a1.y*mf1.y + a1.z*mf1.z + a1.w*mf1.w
                    + a2.x*mf2.x + a2.y*mf2.y + a2.z*mf2.z + a2.w*mf2.w;
#pragma unroll
            for (int off = 32; off > 0; off >>= 1) p += __shfl_down(p, off);
            if (lane == 0) sc[0] = p;
        }
        __syncthreads();
        float s0v   = sc[0];
        float newM  = fmaxf(M, s0v);
        float scale = __expf(M - newM);
        float w0    = __expf(s0v - newM);
        d = d * scale + w0;
        accv0 = accv0 * scale + w0 * tile[0][tid];
        accv1 = accv1 * scale + w0 * tile[0][tid + 256];
        accv2 = accv2 * scale + w0 * tile[0][tid + 512];
        M = newM;
    }

    float* outp = ws + OFF_XPART + (size_t)(part * BB + b) * XPART_STRIDE;
    outp[tid] = accv0; outp[tid + 256] = accv1; outp[tid + 512] = accv2;
    if (tid == 0) { outp[768] = M; outp[769] = d; }
}

// ---------------- K5: y-side weighted sum over t (per (b, quarter)) ------------
__global__ __launch_bounds__(192) void k_yweight(const float* __restrict__ o2,
                                                 float* __restrict__ ws) {
    int part = blockIdx.x & 3, b = blockIdx.x >> 2;
    int tid = threadIdx.x;             // 0..191, one float4 column each
    __shared__ float wl[129];
    int t0 = part * 128;
    const float* arow = ws + OFF_AROW + b * AROW_STRIDE;
    for (int i = tid; i < 129; i += 192) {
        if (i < 128) {
            int t = t0 + i;
            wl[i] = __expf(arow[t] - ws[OFF_COLM + t]) * ws[OFF_COLRD + t];
        } else if (part == 3) {
            wl[128] = __expf(arow[SS] - ws[OFF_COLM + SS]) * ws[OFF_COLRD + SS];
        }
    }
    __syncthreads();
    const float4* base = (const float4*)(o2 + (size_t)b * SS * VV) + tid;
    float4 acc = {0.f, 0.f, 0.f, 0.f};
#pragma unroll 4
    for (int i = 0; i < 128; ++i) {
        float w = wl[i];
        float4 x = base[(size_t)(t0 + i) * 192];
        acc.x += w * x.x; acc.y += w * x.y; acc.z += w * x.z; acc.w += w * x.w;
    }
    if (part == 3) {
        float w = wl[128];
        float4 x = ((const float4*)(ws + OFF_M2 + b * VV))[tid];
        acc.x += w * x.x; acc.y += w * x.y; acc.z += w * x.z; acc.w += w * x.w;
    }
    ((float4*)(ws + OFF_YPART + (size_t)(part * BB + b) * VV))[tid] = acc;
}

// ---------------- K6: epilogue — merge partials, GEMVs, MLP, sigmoid -----------
__global__ __launch_bounds__(256) void k_epilogue(const float* __restrict__ Wg,
                                                  const float* __restrict__ bg,
                                                  const float* __restrict__ Wfd,
                                                  const float* __restrict__ bfd,
                                                  const float* __restrict__ Wff,
                                                  const float* __restrict__ bff,
                                                  float* __restrict__ ws,
                                                  float* __restrict__ out) {
    int b = blockIdx.x;
    int tid = threadIdx.x;
    __shared__ __align__(16) float cx[2 * VV];   // [m1 | atty]  (for o1)
    __shared__ __align__(16) float cy[2 * VV];   // [m2 | attx]  (for o2)
    __shared__ float od[2][HH][2];
    __shared__ float o1s[HH], o2s[HH];

    float Mp[4], dp[4];
#pragma unroll
    for (int p = 0; p < 4; ++p) {
        const float* xp = ws + OFF_XPART + (size_t)(p * BB + b) * XPART_STRIDE;
        Mp[p] = xp[768];
        dp[p] = xp[769];
    }
    float M = fmaxf(fmaxf(Mp[0], Mp[1]), fmaxf(Mp[2], Mp[3]));
    float e[4], den = 0.f;
#pragma unroll
    for (int p = 0; p < 4; ++p) { e[p] = __expf(Mp[p] - M); den += dp[p] * e[p]; }
    float rden = 1.0f / den;

    for (int i = tid; i < VV; i += 256) {
        cx[i] = ws[OFF_M1 + b * VV + i];
        cy[i] = ws[OFF_M2 + b * VV + i];
        float ay = 0.f;
#pragma unroll
        for (int p = 0; p < 4; ++p) ay += ws[OFF_YPART + (size_t)(p * BB + b) * VV + i];
        cx[VV + i] = ay;
        float ax = 0.f;
#pragma unroll
        for (int p = 0; p < 4; ++p) ax += ws[OFF_XPART + (size_t)(p * BB + b) * XPART_STRIDE + i] * e[p];
        cy[VV + i] = ax * rden;
    }
    __syncthreads();

    if (tid < 200) {
        int which = tid / 100, r = tid % 100, h = r >> 1, seg = r & 1;
        const float* c = which ? cy : cx;
        const float4* cc = (const float4*)(c + seg * VV);
        const float4* wg = (const float4*)(Wg + (size_t)h * 2 * VV + seg * VV);
        float acc = 0.f;
        for (int j = 0; j < VV / 4; ++j) {
            float4 a4 = cc[j]; float4 w4 = wg[j];
            acc += a4.x * w4.x + a4.y * w4.y + a4.z * w4.z + a4.w * w4.w;
        }
        od[which][h][seg] = acc;
    }
    __syncthreads();
    if (tid < HH)                     o1s[tid]      = od[0][tid][0]    + od[0][tid][1]    + bg[tid];
    else if (tid >= 64 && tid < 64 + HH) { int h = tid - 64; o2s[h] = od[1][h][0] + od[1][h][1] + bg[h]; }
    __syncthreads();
    if (tid < 64) {
        float hv = 0.f;
        if (tid < HH) {
            float a = bfd[tid];
            for (int k = 0; k < HH; ++k)
                a += o1s[k] * Wfd[tid * 2 * HH + k] + o2s[k] * Wfd[tid * 2 * HH + HH + k];
            hv = fmaxf(a, 0.f) * Wff[tid];
        }
#pragma unroll
        for (int off = 32; off > 0; off >>= 1) hv += __shfl_down(hv, off);
        if (tid == 0) out[b] = 1.0f / (1.0f + __expf(-(hv + bff[0])));
    }
}

extern "C" void kernel_launch(void* const* d_in, const int* in_sizes, int n_in,
                              void* d_out, int out_size, void* d_ws, size_t ws_size,
                              hipStream_t stream) {
    const float* o1  = (const float*)d_in[0];
    const float* o2  = (const float*)d_in[1];
    const float* Wg  = (const float*)d_in[2];
    const float* bg  = (const float*)d_in[3];
    const float* Wfd = (const float*)d_in[4];
    const float* bfd = (const float*)d_in[5];
    const float* Wff = (const float*)d_in[6];
    const float* bff = (const float*)d_in[7];
    float* out = (float*)d_out;
    float* ws  = (float*)d_ws;

    // zero m1/m2 (atomic accumulation targets)
    hipMemsetAsync(ws, 0, (size_t)2 * BB * VV * sizeof(float), stream);

    k_mean1   <<<2048, 192, 0, stream>>>(o1, ws);        // o1 pass 1: m1
    k_o2fused <<<2048, 256, 0, stream>>>(o2, ws);        // o2 pass 1: m2 + y-scores
    k_vrow    <<< 256,  64, 0, stream>>>(ws);            // arow[b,S] = m1.m2
    k_colstats<<< 513, 256, 0, stream>>>(ws);            // softmax-over-b stats
    k_xside   <<<1024, 256, 0, stream>>>(o1, ws);        // o1 pass 2: online softmax
    k_yweight <<<1024, 192, 0, stream>>>(o2, ws);        // o2 pass 2: weighted sum
    k_epilogue<<< 256, 256, 0, stream>>>(Wg, bg, Wfd, bfd, Wff, bff, ws, out);
}